// Round 1
// baseline (616.170 us; speedup 1.0000x reference)
//
#include <hip/hip_runtime.h>
#include <math.h>

// ---------------------------------------------------------------------------
// TransNeXt aggregated attention, fp32 baseline.
// B=4, H=W=64, C=256, NH=8, hd=32, WINDOW=3 (LOCAL_LEN=9), SR=8 (pool 8x8=64)
// ---------------------------------------------------------------------------

#define BM 64
#define BN 64
#define BKK 16

// C[M,N] = act(A[M,K] @ W[N,K]^T + bias[N]); act: 0=none, 1=exact gelu
__global__ __launch_bounds__(256) void gemm_bias_act(
    const float* __restrict__ A, const float* __restrict__ Wt,
    const float* __restrict__ bias, float* __restrict__ Cmat,
    int M, int N, int K, int act)
{
    __shared__ float As[BKK][BM + 4];
    __shared__ float Bs[BKK][BN + 4];
    const int tid = threadIdx.x;
    const int bm = blockIdx.y * BM;
    const int bn = blockIdx.x * BN;
    const int tr = (tid >> 4) << 2;   // 0..60
    const int tc = (tid & 15) << 2;   // 0..60
    const int lr = tid >> 2;          // 0..63 (row within tile for loads)
    const int lc = (tid & 3) << 2;    // 0,4,8,12 (k within tile)
    float acc[4][4] = {{0.f}};

    for (int k0 = 0; k0 < K; k0 += BKK) {
        float4 av = *(const float4*)(A  + (size_t)(bm + lr) * K + k0 + lc);
        float4 wv = *(const float4*)(Wt + (size_t)(bn + lr) * K + k0 + lc);
        As[lc + 0][lr] = av.x; As[lc + 1][lr] = av.y;
        As[lc + 2][lr] = av.z; As[lc + 3][lr] = av.w;
        Bs[lc + 0][lr] = wv.x; Bs[lc + 1][lr] = wv.y;
        Bs[lc + 2][lr] = wv.z; Bs[lc + 3][lr] = wv.w;
        __syncthreads();
#pragma unroll
        for (int kk = 0; kk < BKK; ++kk) {
            float4 a  = *(const float4*)&As[kk][tr];
            float4 bq = *(const float4*)&Bs[kk][tc];
            float av4[4] = {a.x, a.y, a.z, a.w};
            float bv4[4] = {bq.x, bq.y, bq.z, bq.w};
#pragma unroll
            for (int ii = 0; ii < 4; ++ii)
#pragma unroll
                for (int jj = 0; jj < 4; ++jj)
                    acc[ii][jj] = fmaf(av4[ii], bv4[jj], acc[ii][jj]);
        }
        __syncthreads();
    }
#pragma unroll
    for (int ii = 0; ii < 4; ++ii) {
        int m = bm + tr + ii;
#pragma unroll
        for (int jj = 0; jj < 4; ++jj) {
            int nn = bn + tc + jj;
            float v = acc[ii][jj] + bias[nn];
            if (act == 1) v = 0.5f * v * (1.0f + erff(v * 0.70710678118654752f));
            Cmat[(size_t)m * N + nn] = v;
        }
    }
}

// L2-normalize groups of 32 channels within the first 256 channels of each row
__global__ __launch_bounds__(256) void headnorm(float* __restrict__ buf, int rowStride)
{
    size_t row = blockIdx.x;
    int tid = threadIdx.x;
    float* p = buf + row * (size_t)rowStride + tid;
    float v = *p;
    float ss = v * v;
#pragma unroll
    for (int off = 16; off; off >>= 1) ss += __shfl_xor(ss, off, 32);
    *p = v / fmaxf(sqrtf(ss), 1e-12f);
}

// 8x8 average pool of x_sr (stored (B,N,C)) + LayerNorm over C -> xpool (B,64,C)
__global__ __launch_bounds__(256) void pool_ln(
    const float* __restrict__ xsr, const float* __restrict__ g,
    const float* __restrict__ be, float* __restrict__ xpool, int Hh, int Ww)
{
    const int C = 256;
    const int Nn = Hh * Ww;
    int b = blockIdx.x >> 6;
    int pidx = blockIdx.x & 63;
    int ph = pidx >> 3, pw = pidx & 7;
    int tid = threadIdx.x;
    float s = 0.f;
    for (int si = 0; si < 8; ++si) {
        int i = ph * 8 + si;
        const float* rowp = xsr + ((size_t)b * Nn + (size_t)i * Ww + pw * 8) * C + tid;
#pragma unroll
        for (int sj = 0; sj < 8; ++sj) s += rowp[(size_t)sj * C];
    }
    s *= (1.f / 64.f);
    __shared__ float red[256];
    red[tid] = s; __syncthreads();
    for (int st = 128; st; st >>= 1) { if (tid < st) red[tid] += red[tid + st]; __syncthreads(); }
    float mean = red[0] * (1.f / 256.f);
    __syncthreads();
    float dv = s - mean;
    red[tid] = dv * dv; __syncthreads();
    for (int st = 128; st; st >>= 1) { if (tid < st) red[tid] += red[tid + st]; __syncthreads(); }
    float var = red[0] * (1.f / 256.f);
    xpool[(size_t)blockIdx.x * C + tid] = dv * rsqrtf(var + 1e-5f) * g[tid] + be[tid];
}

// cpb = relu(table @ fc1^T + b1) @ fc2^T + b2   (table: (T,2), out: (T,8))
__global__ __launch_bounds__(256) void cpb_mlp(
    const float* __restrict__ table, const float* __restrict__ w1,
    const float* __restrict__ b1, const float* __restrict__ w2,
    const float* __restrict__ b2, float* __restrict__ outc)
{
    int row = blockIdx.x;
    float t0 = table[(size_t)row * 2], t1 = table[(size_t)row * 2 + 1];
    int tid = threadIdx.x;
    int tid2 = tid + 256;
    float h0 = fmaxf(fmaf(t1, w1[tid * 2 + 1],  fmaf(t0, w1[tid * 2],  b1[tid])),  0.f);
    float h1 = fmaxf(fmaf(t1, w1[tid2 * 2 + 1], fmaf(t0, w1[tid2 * 2], b1[tid2])), 0.f);
    __shared__ float red[256];
    for (int hh = 0; hh < 8; ++hh) {
        red[tid] = h0 * w2[hh * 512 + tid] + h1 * w2[hh * 512 + tid2];
        __syncthreads();
        for (int st = 128; st; st >>= 1) { if (tid < st) red[tid] += red[tid + st]; __syncthreads(); }
        if (tid == 0) outc[(size_t)row * 8 + hh] = red[0] + b2[hh];
        __syncthreads();
    }
}

// Fused attention: one block per (b,n); 8 heads x 32 lanes.
__global__ __launch_bounds__(256) void attn_fused(
    const float* __restrict__ qn,   // (B,N,256) q_norm
    const float* __restrict__ kv,   // (B,N,512) ch 0..255 = k (normed), 256..511 = v
    const float* __restrict__ kvp,  // (B,64,512) same layout (k part normed)
    const float* __restrict__ cpbT, // (T,8)
    const int*   __restrict__ rpi,  // (N*64)
    const float* __restrict__ sls,  // (N,1)
    const float* __restrict__ temp, // (8)
    const float* __restrict__ qe,   // (8,32)
    const float* __restrict__ rbl,  // (8,9)
    const float* __restrict__ ltok, // (8,32,9)
    const float* __restrict__ lbias,// (8,9)
    float* __restrict__ attno,      // (B,N,256)
    int Hh, int Ww)
{
    const int C = 256;
    const int Nn = Hh * Ww;
    int bn = blockIdx.x;
    int b = bn / Nn, n = bn % Nn;
    int i = n / Ww, j = n % Ww;
    int tid = threadIdx.x;
    int h = tid >> 5, d = tid & 31;

    float qnv = qn[(size_t)bn * C + tid];
    float t = temp[h];
    float sp = (t > 20.f) ? t : log1pf(expf(t));       // softplus
    float scale = sp * sls[n];
    float qs = (qnv + qe[(h << 5) + d]) * scale;

    __shared__ float qs_sh[256];
    __shared__ float qn_sh[256];
    qs_sh[tid] = qs; qn_sh[tid] = qnv;
    __syncthreads();

    // ---- local scores (9 taps); OOB -> -inf (matches padding_mask) ----
    float my_loc = -INFINITY;
#pragma unroll
    for (int l = 0; l < 9; ++l) {
        int ii = i + l / 3 - 1, jj = j + l % 3 - 1;
        if (ii >= 0 && ii < Hh && jj >= 0 && jj < Ww) {   // uniform over the 32-lane group
            int nl = ii * Ww + jj;
            float kvv = kv[((size_t)b * Nn + nl) * 512 + (h << 5) + d];
            float p = qs * kvv;
#pragma unroll
            for (int off = 16; off; off >>= 1) p += __shfl_xor(p, off, 32);
            if (d == l) my_loc = p + rbl[h * 9 + l];
        }
    }

    // ---- pool scores: lane handles p=d and p=d+32 ----
    int idx0 = rpi[(size_t)n * 64 + d];
    int idx1 = rpi[(size_t)n * 64 + 32 + d];
    float pb0 = cpbT[(size_t)idx0 * 8 + h];
    float pb1 = cpbT[(size_t)idx1 * 8 + h];
    const float* qsl = qs_sh + (h << 5);
    const float* kp0 = kvp + ((size_t)(b * 64 + d)) * 512 + (h << 5);
    const float* kp1 = kp0 + 32 * 512;
    float s0 = 0.f, s1 = 0.f;
#pragma unroll
    for (int dd = 0; dd < 32; dd += 4) {
        float4 qv = *(const float4*)(qsl + dd);
        float4 k0 = *(const float4*)(kp0 + dd);
        float4 k1 = *(const float4*)(kp1 + dd);
        s0 += qv.x * k0.x + qv.y * k0.y + qv.z * k0.z + qv.w * k0.w;
        s1 += qv.x * k1.x + qv.y * k1.y + qv.z * k1.z + qv.w * k1.w;
    }
    float my_p0 = s0 + pb0, my_p1 = s1 + pb1;

    // ---- softmax over 9 + 64 = 73 scores (within the 32-lane group) ----
    float m = fmaxf(my_loc, fmaxf(my_p0, my_p1));
#pragma unroll
    for (int off = 16; off; off >>= 1) m = fmaxf(m, __shfl_xor(m, off, 32));
    float el = expf(my_loc - m);   // -inf -> 0 for lanes >= 9 / masked taps
    float e0 = expf(my_p0 - m);
    float e1 = expf(my_p1 - m);
    float ssum = el + e0 + e1;
#pragma unroll
    for (int off = 16; off; off >>= 1) ssum += __shfl_xor(ssum, off, 32);
    float inv = 1.0f / ssum;
    float a_l = el * inv, a0 = e0 * inv, a1 = e1 * inv;

    // ---- lt[l] = q_norm . learnable_tokens[h,:,l] + lbias + a_loc[l] ----
    float ltv = 0.f;
    if (d < 9) {
        const float* qnl = qn_sh + (h << 5);
        const float* lw = ltok + h * 288 + d;   // stride 9 over dd
#pragma unroll
        for (int dd = 0; dd < 32; ++dd) ltv += qnl[dd] * lw[dd * 9];
        ltv += lbias[h * 9 + d] + a_l;
    }

    // ---- output: sum_l lt[l]*v_local + sum_p a_pool[p]*v_pool ----
    float outv = 0.f;
#pragma unroll
    for (int l = 0; l < 9; ++l) {
        float ltl = __shfl(ltv, l, 32);
        int ii = i + l / 3 - 1, jj = j + l % 3 - 1;
        if (ii >= 0 && ii < Hh && jj >= 0 && jj < Ww) {  // v is zero-padded: skip OOB
            int nl = ii * Ww + jj;
            outv += ltl * kv[((size_t)b * Nn + nl) * 512 + 256 + (h << 5) + d];
        }
    }
    const float* vp = kvp + (size_t)(b * 64) * 512 + 256 + (h << 5) + d;
#pragma unroll
    for (int p = 0; p < 32; ++p) {
        float ap = __shfl(a0, p, 32);
        outv += ap * vp[(size_t)p * 512];
    }
#pragma unroll
    for (int p = 0; p < 32; ++p) {
        float ap = __shfl(a1, p, 32);
        outv += ap * vp[(size_t)(32 + p) * 512];
    }
    attno[(size_t)bn * C + tid] = outv;
}

extern "C" void kernel_launch(void* const* d_in, const int* in_sizes, int n_in,
                              void* d_out, int out_size, void* d_ws, size_t ws_size,
                              hipStream_t stream)
{
    const float* x    = (const float*)d_in[0];
    const float* tbl  = (const float*)d_in[1];
    const float* sls  = (const float*)d_in[2];
    const float* q_w  = (const float*)d_in[3];
    const float* q_b  = (const float*)d_in[4];
    const float* kv_w = (const float*)d_in[5];
    const float* kv_b = (const float*)d_in[6];
    const float* temp = (const float*)d_in[7];
    const float* qe   = (const float*)d_in[8];
    const float* sr_w = (const float*)d_in[9];
    const float* sr_b = (const float*)d_in[10];
    const float* ng   = (const float*)d_in[11];
    const float* nb   = (const float*)d_in[12];
    const float* f1w  = (const float*)d_in[13];
    const float* f1b  = (const float*)d_in[14];
    const float* f2w  = (const float*)d_in[15];
    const float* f2b  = (const float*)d_in[16];
    const float* rbl  = (const float*)d_in[17];
    const float* ltok = (const float*)d_in[18];
    const float* lbias= (const float*)d_in[19];
    const float* pw   = (const float*)d_in[20];
    const float* pb   = (const float*)d_in[21];
    const int*   rpi  = (const int*)d_in[22];
    // d_in[23] padding_mask (bool) — recomputed from geometry on device
    // d_in[24]=H, d_in[25]=W — fixed 64x64 for this problem

    const int C = 256, Hh = 64, Ww = 64, Nn = Hh * Ww;
    const int B = in_sizes[0] / (Nn * C);   // = 4
    const int T = in_sizes[1] / 2;          // cpb table rows
    const int M = B * Nn;                   // 16384

    float* ws = (float*)d_ws;
    size_t o = 0;
    float* qbuf  = ws + o; o += (size_t)M * C;
    float* kvbuf = ws + o; o += (size_t)M * 2 * C;
    float* xsr   = ws + o; o += (size_t)M * C;
    float* xpool = ws + o; o += (size_t)B * 64 * C;
    float* kvp   = ws + o; o += (size_t)B * 64 * 2 * C;
    float* cpbB  = ws + o; o += (size_t)T * 8;
    float* attno = xsr;    // xsr is dead after pool_ln; reuse for attention output

    dim3 blk(256);
    // q = x @ q_w^T + q_b
    gemm_bias_act<<<dim3(C / BN, M / BM), blk, 0, stream>>>(x, q_w, q_b, qbuf, M, C, C, 0);
    // kv = x @ kv_w^T + kv_b
    gemm_bias_act<<<dim3(2 * C / BN, M / BM), blk, 0, stream>>>(x, kv_w, kv_b, kvbuf, M, 2 * C, C, 0);
    // x_sr = gelu(x @ sr_w^T + sr_b)
    gemm_bias_act<<<dim3(C / BN, M / BM), blk, 0, stream>>>(x, sr_w, sr_b, xsr, M, C, C, 1);
    // normalize q per head (in place) and k half of kv (in place)
    headnorm<<<M, blk, 0, stream>>>(qbuf, C);
    headnorm<<<M, blk, 0, stream>>>(kvbuf, 2 * C);
    // 8x8 avg pool + layernorm
    pool_ln<<<B * 64, blk, 0, stream>>>(xsr, ng, nb, xpool, Hh, Ww);
    // kv_p = x_pool @ kv_w^T + kv_b ; normalize k half
    gemm_bias_act<<<dim3(2 * C / BN, (B * 64) / BM), blk, 0, stream>>>(xpool, kv_w, kv_b, kvp, B * 64, 2 * C, C, 0);
    headnorm<<<B * 64, blk, 0, stream>>>(kvp, 2 * C);
    // cpb MLP
    cpb_mlp<<<T, blk, 0, stream>>>(tbl, f1w, f1b, f2w, f2b, cpbB);
    // fused attention
    attn_fused<<<M, blk, 0, stream>>>(qbuf, kvbuf, kvp, cpbB, rpi, sls, temp, qe, rbl, ltok, lbias, attno, Hh, Ww);
    // out = attno @ proj_w^T + proj_b
    gemm_bias_act<<<dim3(C / BN, M / BM), blk, 0, stream>>>(attno, pw, pb, (float*)d_out, M, C, C, 0);
}

// Round 2
// 520.233 us; speedup vs baseline: 1.1844x; 1.1844x over previous
//
#include <hip/hip_runtime.h>
#include <math.h>

// ---------------------------------------------------------------------------
// TransNeXt aggregated attention. Round 2: restructured fp32 attention
// (one block per (b,head,row); register-blocked pool GEMM; no shfl chains).
// B=4, H=W=64, C=256, NH=8, hd=32, WINDOW=3 (LOCAL_LEN=9), SR=8 (pool 8x8=64)
// ---------------------------------------------------------------------------

#define BM 64
#define BN 64
#define BKK 16

// C[M,N] = act(A[M,K] @ W[N,K]^T + bias[N]); act: 0=none, 1=exact gelu
__global__ __launch_bounds__(256) void gemm_bias_act(
    const float* __restrict__ A, const float* __restrict__ Wt,
    const float* __restrict__ bias, float* __restrict__ Cmat,
    int M, int N, int K, int act)
{
    __shared__ float As[BKK][BM + 4];
    __shared__ float Bs[BKK][BN + 4];
    const int tid = threadIdx.x;
    const int bm = blockIdx.y * BM;
    const int bn = blockIdx.x * BN;
    const int tr = (tid >> 4) << 2;
    const int tc = (tid & 15) << 2;
    const int lr = tid >> 2;
    const int lc = (tid & 3) << 2;
    float acc[4][4] = {{0.f}};

    for (int k0 = 0; k0 < K; k0 += BKK) {
        float4 av = *(const float4*)(A  + (size_t)(bm + lr) * K + k0 + lc);
        float4 wv = *(const float4*)(Wt + (size_t)(bn + lr) * K + k0 + lc);
        As[lc + 0][lr] = av.x; As[lc + 1][lr] = av.y;
        As[lc + 2][lr] = av.z; As[lc + 3][lr] = av.w;
        Bs[lc + 0][lr] = wv.x; Bs[lc + 1][lr] = wv.y;
        Bs[lc + 2][lr] = wv.z; Bs[lc + 3][lr] = wv.w;
        __syncthreads();
#pragma unroll
        for (int kk = 0; kk < BKK; ++kk) {
            float4 a  = *(const float4*)&As[kk][tr];
            float4 bq = *(const float4*)&Bs[kk][tc];
            float av4[4] = {a.x, a.y, a.z, a.w};
            float bv4[4] = {bq.x, bq.y, bq.z, bq.w};
#pragma unroll
            for (int ii = 0; ii < 4; ++ii)
#pragma unroll
                for (int jj = 0; jj < 4; ++jj)
                    acc[ii][jj] = fmaf(av4[ii], bv4[jj], acc[ii][jj]);
        }
        __syncthreads();
    }
#pragma unroll
    for (int ii = 0; ii < 4; ++ii) {
        int m = bm + tr + ii;
#pragma unroll
        for (int jj = 0; jj < 4; ++jj) {
            int nn = bn + tc + jj;
            float v = acc[ii][jj] + bias[nn];
            if (act == 1) v = 0.5f * v * (1.0f + erff(v * 0.70710678118654752f));
            Cmat[(size_t)m * N + nn] = v;
        }
    }
}

// L2-normalize groups of 32 channels within the first 256 channels of each row
__global__ __launch_bounds__(256) void headnorm(float* __restrict__ buf, int rowStride)
{
    size_t row = blockIdx.x;
    int tid = threadIdx.x;
    float* p = buf + row * (size_t)rowStride + tid;
    float v = *p;
    float ss = v * v;
#pragma unroll
    for (int off = 16; off; off >>= 1) ss += __shfl_xor(ss, off, 32);
    *p = v / fmaxf(sqrtf(ss), 1e-12f);
}

// 8x8 average pool of x_sr (stored (B,N,C)) + LayerNorm over C -> xpool (B,64,C)
__global__ __launch_bounds__(256) void pool_ln(
    const float* __restrict__ xsr, const float* __restrict__ g,
    const float* __restrict__ be, float* __restrict__ xpool, int Hh, int Ww)
{
    const int C = 256;
    const int Nn = Hh * Ww;
    int b = blockIdx.x >> 6;
    int pidx = blockIdx.x & 63;
    int ph = pidx >> 3, pw = pidx & 7;
    int tid = threadIdx.x;
    float s = 0.f;
    for (int si = 0; si < 8; ++si) {
        int i = ph * 8 + si;
        const float* rowp = xsr + ((size_t)b * Nn + (size_t)i * Ww + pw * 8) * C + tid;
#pragma unroll
        for (int sj = 0; sj < 8; ++sj) s += rowp[(size_t)sj * C];
    }
    s *= (1.f / 64.f);
    __shared__ float red[256];
    red[tid] = s; __syncthreads();
    for (int st = 128; st; st >>= 1) { if (tid < st) red[tid] += red[tid + st]; __syncthreads(); }
    float mean = red[0] * (1.f / 256.f);
    __syncthreads();
    float dv = s - mean;
    red[tid] = dv * dv; __syncthreads();
    for (int st = 128; st; st >>= 1) { if (tid < st) red[tid] += red[tid + st]; __syncthreads(); }
    float var = red[0] * (1.f / 256.f);
    xpool[(size_t)blockIdx.x * C + tid] = dv * rsqrtf(var + 1e-5f) * g[tid] + be[tid];
}

// cpb = relu(table @ fc1^T + b1) @ fc2^T + b2   (table: (T,2), out: (T,8))
__global__ __launch_bounds__(256) void cpb_mlp(
    const float* __restrict__ table, const float* __restrict__ w1,
    const float* __restrict__ b1, const float* __restrict__ w2,
    const float* __restrict__ b2, float* __restrict__ outc)
{
    int row = blockIdx.x;
    float t0 = table[(size_t)row * 2], t1 = table[(size_t)row * 2 + 1];
    int tid = threadIdx.x;
    int tid2 = tid + 256;
    float h0 = fmaxf(fmaf(t1, w1[tid * 2 + 1],  fmaf(t0, w1[tid * 2],  b1[tid])),  0.f);
    float h1 = fmaxf(fmaf(t1, w1[tid2 * 2 + 1], fmaf(t0, w1[tid2 * 2], b1[tid2])), 0.f);
    __shared__ float red[256];
    for (int hh = 0; hh < 8; ++hh) {
        red[tid] = h0 * w2[hh * 512 + tid] + h1 * w2[hh * 512 + tid2];
        __syncthreads();
        for (int st = 128; st; st >>= 1) { if (tid < st) red[tid] += red[tid + st]; __syncthreads(); }
        if (tid == 0) outc[(size_t)row * 8 + hh] = red[0] + b2[hh];
        __syncthreads();
    }
}

// ---------------------------------------------------------------------------
// attn_fused_v2: block = (row i, head h, batch b). 256 threads = 4 waves.
// Wave w, lane j (0..63): query j of the row; wave owns pool tokens w*16..+15.
// ---------------------------------------------------------------------------
__global__ __launch_bounds__(256) void attn_fused_v2(
    const float* __restrict__ qn,   // (B,N,256) q_norm
    const float* __restrict__ kv,   // (B,N,512) 0..255 = k (normed), 256..511 = v
    const float* __restrict__ kvp,  // (B,64,512) same layout (k part normed)
    const float* __restrict__ cpbT, // (T,8)
    const int*   __restrict__ rpi,  // (N*64)
    const float* __restrict__ sls,  // (N,1)
    const float* __restrict__ temp, // (8)
    const float* __restrict__ qe,   // (8,32)
    const float* __restrict__ rbl,  // (8,9)
    const float* __restrict__ ltok, // (8,32,9)
    const float* __restrict__ lbias,// (8,9)
    float* __restrict__ attno)      // (B,N,256)
{
    const int Hh = 64, Ww = 64, Nn = 4096;
    const int i = blockIdx.x;      // image row
    const int h = blockIdx.y;      // head
    const int b = blockIdx.z;      // batch
    const int t = threadIdx.x;
    const int w = t >> 6;          // wave 0..3
    const int lane = t & 63;       // query j for phases 2-4

    __shared__ float q_s [64][33];   // scaled q, scalar-read layout
    __shared__ float kp_s[64][36];   // k_pool row-aligned for float4 broadcast
    __shared__ float vp_s[64][36];
    __shared__ float oacc[64][33];   // pool AV accumulator
    __shared__ float SL [64][10];    // local scores -> local weights (AL)
    __shared__ float LT [64][10];    // learnable-token dot + lbias
    __shared__ float lt_s[288];      // ltok[h] slice (d*9 + l)
    __shared__ float qe_s[32];
    __shared__ float pmax[4][64];
    __shared__ float psum[4][64];
    __shared__ float sp_sh;

    const float tmp = temp[h];
    const float sp = (tmp > 20.f) ? tmp : log1pf(expf(tmp));   // softplus
    if (t == 0) sp_sh = sp;

    // ---------- phase 0: stage q (scaled), k_pool, v_pool ----------
    {
        const int d = t & 31;
        const int jb = t >> 5;             // 0..7
#pragma unroll
        for (int kq = 0; kq < 8; ++kq) {
            const int j = jb + kq * 8;
            const int n = i * 64 + j;
            float qv = qn[((size_t)(b * Nn + n)) * 256 + h * 32 + d];
            q_s[j][d] = (qv + qe[h * 32 + d]) * sp * sls[n];
            const int p = j;
            kp_s[p][d] = kvp[((size_t)(b * 64 + p)) * 512 + h * 32 + d];
            vp_s[p][d] = kvp[((size_t)(b * 64 + p)) * 512 + 256 + h * 32 + d];
        }
        if (t < 288) lt_s[t] = ltok[h * 288 + t];
        else if (t < 320) lt_s[t - 288 + 256 - 256] = lt_s[t - 288]; // no-op filler
        if (t >= 224 && t < 256) { int u = t - 224 + 256; lt_s[u] = ltok[h * 288 + u]; }
        if (t < 32) qe_s[t] = qe[h * 32 + t];
    }
    __syncthreads();

    // ---------- phase 1: local scores (SL) + learnable-token dots (LT) ----------
    // 576 tasks: (j,l) = task/9, task%9
    {
#pragma unroll
        for (int rep = 0; rep < 3; ++rep) {
            const int task = t + rep * 256;
            if (task < 576) {
                const int j = task / 9, l = task % 9;
                const int ii = i + l / 3 - 1, jj = j + l % 3 - 1;
                const int n = i * 64 + j;
                const float inv_scale = 1.0f / (sp * sls[n]);
                if (ii >= 0 && ii < Hh && jj >= 0 && jj < Ww) {
                    const float* krow = kv + ((size_t)(b * Nn + ii * 64 + jj)) * 512 + h * 32;
                    float dk = 0.f, dl = 0.f;
#pragma unroll
                    for (int dd = 0; dd < 32; dd += 4) {
                        float4 k4 = *(const float4*)(krow + dd);
                        float q0 = q_s[j][dd + 0], q1 = q_s[j][dd + 1];
                        float q2 = q_s[j][dd + 2], q3 = q_s[j][dd + 3];
                        dk += q0 * k4.x + q1 * k4.y + q2 * k4.z + q3 * k4.w;
                        // reconstruct q_norm = q_scaled*inv_scale - qe
                        dl += (q0 * inv_scale - qe_s[dd + 0]) * lt_s[(dd + 0) * 9 + l]
                            + (q1 * inv_scale - qe_s[dd + 1]) * lt_s[(dd + 1) * 9 + l]
                            + (q2 * inv_scale - qe_s[dd + 2]) * lt_s[(dd + 2) * 9 + l]
                            + (q3 * inv_scale - qe_s[dd + 3]) * lt_s[(dd + 3) * 9 + l];
                    }
                    SL[j][l] = dk + rbl[h * 9 + l];
                    LT[j][l] = dl + lbias[h * 9 + l];
                } else {
                    SL[j][l] = -INFINITY;
                    LT[j][l] = 0.f;
                }
            }
        }
    }
    __syncthreads();

    // ---------- phase 2: pool scores (registers) ----------
    const int j = lane;
    const int n64 = (i * 64 + j) * 64;
    float qr[32];
#pragma unroll
    for (int dd = 0; dd < 32; ++dd) qr[dd] = q_s[j][dd];

    float sc[16];
#pragma unroll
    for (int pp = 0; pp < 16; ++pp) {
        const int p = w * 16 + pp;
        const float4* kr = (const float4*)&kp_s[p][0];
        float acc = 0.f;
#pragma unroll
        for (int c = 0; c < 8; ++c) {
            float4 k4 = kr[c];
            acc += qr[4 * c + 0] * k4.x + qr[4 * c + 1] * k4.y
                 + qr[4 * c + 2] * k4.z + qr[4 * c + 3] * k4.w;
        }
        const int idx = rpi[n64 + p];
        sc[pp] = acc + cpbT[(size_t)idx * 8 + h];
    }

    // ---------- phase 3: softmax over 64 pool + 9 local ----------
    float pm = sc[0];
#pragma unroll
    for (int pp = 1; pp < 16; ++pp) pm = fmaxf(pm, sc[pp]);
    pmax[w][j] = pm;
    __syncthreads();
    float m = fmaxf(fmaxf(pmax[0][j], pmax[1][j]), fmaxf(pmax[2][j], pmax[3][j]));
#pragma unroll
    for (int l = 0; l < 9; ++l) m = fmaxf(m, SL[j][l]);

    float e[16];
    float ps = 0.f;
#pragma unroll
    for (int pp = 0; pp < 16; ++pp) { e[pp] = expf(sc[pp] - m); ps += e[pp]; }
    float el[9];
    if (w == 0) {
#pragma unroll
        for (int l = 0; l < 9; ++l) { el[l] = expf(SL[j][l] - m); ps += el[l]; }
    }
    psum[w][j] = ps;
    __syncthreads();
    const float tot = psum[0][j] + psum[1][j] + psum[2][j] + psum[3][j];
    const float inv = 1.0f / tot;
#pragma unroll
    for (int pp = 0; pp < 16; ++pp) e[pp] *= inv;
    if (w == 0) {
#pragma unroll
        for (int l = 0; l < 9; ++l) SL[j][l] = el[l] * inv + LT[j][l];  // AL in place
    }

    // ---------- phase 4: pool AV (registers), cross-wave reduce in LDS ----------
    float op[32];
#pragma unroll
    for (int dd = 0; dd < 32; ++dd) op[dd] = 0.f;
#pragma unroll
    for (int pp = 0; pp < 16; ++pp) {
        const int p = w * 16 + pp;
        const float av = e[pp];
        const float4* vr = (const float4*)&vp_s[p][0];
#pragma unroll
        for (int c = 0; c < 8; ++c) {
            float4 v4 = vr[c];
            op[4 * c + 0] += av * v4.x; op[4 * c + 1] += av * v4.y;
            op[4 * c + 2] += av * v4.z; op[4 * c + 3] += av * v4.w;
        }
    }
#pragma unroll
    for (int r = 0; r < 4; ++r) {
        if (w == r) {
            if (r == 0) {
#pragma unroll
                for (int dd = 0; dd < 32; ++dd) oacc[j][dd] = op[dd];
            } else {
#pragma unroll
                for (int dd = 0; dd < 32; ++dd) oacc[j][dd] += op[dd];
            }
        }
        __syncthreads();
    }

    // ---------- phase 5: local AV + store ----------
    {
        const int d = t & 31;
        const int jb = t >> 5;
#pragma unroll
        for (int kq = 0; kq < 8; ++kq) {
            const int jq = jb + kq * 8;
            float acc = oacc[jq][d];
#pragma unroll
            for (int l = 0; l < 9; ++l) {
                const int ii = i + l / 3 - 1, jj = jq + l % 3 - 1;
                if (ii >= 0 && ii < Hh && jj >= 0 && jj < Ww) {
                    acc += SL[jq][l] *
                        kv[((size_t)(b * Nn + ii * 64 + jj)) * 512 + 256 + h * 32 + d];
                }
            }
            attno[((size_t)(b * Nn + i * 64 + jq)) * 256 + h * 32 + d] = acc;
        }
    }
}

extern "C" void kernel_launch(void* const* d_in, const int* in_sizes, int n_in,
                              void* d_out, int out_size, void* d_ws, size_t ws_size,
                              hipStream_t stream)
{
    const float* x    = (const float*)d_in[0];
    const float* tbl  = (const float*)d_in[1];
    const float* sls  = (const float*)d_in[2];
    const float* q_w  = (const float*)d_in[3];
    const float* q_b  = (const float*)d_in[4];
    const float* kv_w = (const float*)d_in[5];
    const float* kv_b = (const float*)d_in[6];
    const float* temp = (const float*)d_in[7];
    const float* qe   = (const float*)d_in[8];
    const float* sr_w = (const float*)d_in[9];
    const float* sr_b = (const float*)d_in[10];
    const float* ng   = (const float*)d_in[11];
    const float* nb   = (const float*)d_in[12];
    const float* f1w  = (const float*)d_in[13];
    const float* f1b  = (const float*)d_in[14];
    const float* f2w  = (const float*)d_in[15];
    const float* f2b  = (const float*)d_in[16];
    const float* rbl  = (const float*)d_in[17];
    const float* ltok = (const float*)d_in[18];
    const float* lbias= (const float*)d_in[19];
    const float* pw   = (const float*)d_in[20];
    const float* pb   = (const float*)d_in[21];
    const int*   rpi  = (const int*)d_in[22];
    // d_in[23] padding_mask (bool) — recomputed from geometry on device
    // d_in[24]=H, d_in[25]=W — fixed 64x64 for this problem

    const int C = 256, Hh = 64, Ww = 64, Nn = Hh * Ww;
    const int B = in_sizes[0] / (Nn * C);   // = 4
    const int T = in_sizes[1] / 2;          // cpb table rows
    const int M = B * Nn;                   // 16384

    float* ws = (float*)d_ws;
    size_t o = 0;
    float* qbuf  = ws + o; o += (size_t)M * C;
    float* kvbuf = ws + o; o += (size_t)M * 2 * C;
    float* xsr   = ws + o; o += (size_t)M * C;
    float* xpool = ws + o; o += (size_t)B * 64 * C;
    float* kvp   = ws + o; o += (size_t)B * 64 * 2 * C;
    float* cpbB  = ws + o; o += (size_t)T * 8;
    float* attno = xsr;    // xsr dead after pool_ln; reuse for attention output

    dim3 blk(256);
    gemm_bias_act<<<dim3(C / BN, M / BM), blk, 0, stream>>>(x, q_w, q_b, qbuf, M, C, C, 0);
    gemm_bias_act<<<dim3(2 * C / BN, M / BM), blk, 0, stream>>>(x, kv_w, kv_b, kvbuf, M, 2 * C, C, 0);
    gemm_bias_act<<<dim3(C / BN, M / BM), blk, 0, stream>>>(x, sr_w, sr_b, xsr, M, C, C, 1);
    headnorm<<<M, blk, 0, stream>>>(qbuf, C);
    headnorm<<<M, blk, 0, stream>>>(kvbuf, 2 * C);
    pool_ln<<<B * 64, blk, 0, stream>>>(xsr, ng, nb, xpool, Hh, Ww);
    gemm_bias_act<<<dim3(2 * C / BN, (B * 64) / BM), blk, 0, stream>>>(xpool, kv_w, kv_b, kvp, B * 64, 2 * C, C, 0);
    headnorm<<<B * 64, blk, 0, stream>>>(kvp, 2 * C);
    cpb_mlp<<<T, blk, 0, stream>>>(tbl, f1w, f1b, f2w, f2b, cpbB);
    attn_fused_v2<<<dim3(Hh, 8, B), blk, 0, stream>>>(
        qbuf, kvbuf, kvp, cpbB, rpi, sls, temp, qe, rbl, ltok, lbias, attno);
    gemm_bias_act<<<dim3(C / BN, M / BM), blk, 0, stream>>>(attno, pw, pb, (float*)d_out, M, C, C, 0);
}

// Round 3
// 440.080 us; speedup vs baseline: 1.4001x; 1.1821x over previous
//
#include <hip/hip_runtime.h>
#include <math.h>

// ---------------------------------------------------------------------------
// TransNeXt aggregated attention. Round 3: bf16 MFMA GEMMs.
//  - [q | k] GEMM in split-bf16x2 (3 MFMAs, ~fp32 accurate: protects logits)
//  - [v | sr] and proj GEMMs in plain bf16 (linear error paths)
//  - attention kernel unchanged from round 2 (next target)
// B=4, H=W=64, C=256, NH=8, hd=32, LOCAL_LEN=9, pool 8x8=64
// ---------------------------------------------------------------------------

typedef unsigned short ushort_t;
typedef __attribute__((ext_vector_type(8))) short short8;
typedef __attribute__((ext_vector_type(4))) float f32x4;

static __device__ __forceinline__ unsigned short f2bf(float f) {
    unsigned int u = __float_as_uint(f);
    unsigned int lsb = (u >> 16) & 1u;
    u += 0x7fffu + lsb;                 // round-to-nearest-even
    return (unsigned short)(u >> 16);
}
static __device__ __forceinline__ float bf2f(unsigned short h) {
    return __uint_as_float(((unsigned int)h) << 16);
}

#define GLOAD16(g, l)                                                        \
    __builtin_amdgcn_global_load_lds(                                        \
        (const __attribute__((address_space(1))) unsigned int*)(g),          \
        (__attribute__((address_space(3))) unsigned int*)(l), 16, 0, 0)

// ---------------------------------------------------------------------------
// MFMA GEMM: C = A @ W^T + bias. A: (M,256) bf16 (hi/lo), W: (N,256) bf16.
// 128x128 tile, BK=32, 256 thr = 2x2 waves x (4x4) 16x16x32 MFMAs.
// mode 0: N=512, col<256 -> out0=qbuf (stride 256); col>=256 -> out1=kvbuf k-half (stride 512)
// mode 1: N=512, col<256 -> out0=kvbuf v-half (stride 512, +256); col>=256 -> gelu -> out1=xsr
// mode 2: N=256, out0 (stride 256)
// ---------------------------------------------------------------------------
template <bool SPLIT>
__global__ __launch_bounds__(256) void mfma_gemm(
    const ushort_t* __restrict__ Ahi_g, const ushort_t* __restrict__ Alo_g,
    const ushort_t* __restrict__ Bhi_g, const ushort_t* __restrict__ Blo_g,
    const float* __restrict__ bias, float* __restrict__ out0,
    float* __restrict__ out1, int mode)
{
    const int K = 256;
    __shared__ ushort_t Ah[128 * 32];
    __shared__ ushort_t Bh[128 * 32];
    __shared__ ushort_t Al[SPLIT ? 128 * 32 : 8];
    __shared__ ushort_t Bl[SPLIT ? 128 * 32 : 8];

    const int t = threadIdx.x;
    const int w = t >> 6;            // wave 0..3
    const int lane = t & 63;
    const int bm = blockIdx.y * 128;
    const int bn = blockIdx.x * 128;
    const int wm = (w >> 1) * 64;    // wave row offset in tile
    const int wn = (w & 1) * 64;     // wave col offset in tile

    f32x4 acc[4][4];
#pragma unroll
    for (int i = 0; i < 4; ++i)
#pragma unroll
        for (int j = 0; j < 4; ++j) acc[i][j] = f32x4{0.f, 0.f, 0.f, 0.f};

    const int lrow = lane >> 2;         // 0..15
    const int lk8  = (lane & 3) * 8;    // 0,8,16,24

    for (int k0 = 0; k0 < K; k0 += 32) {
#pragma unroll
        for (int r = 0; r < 2; ++r) {
            const int rowoff = r * 64 + w * 16;             // wave-uniform
            const int arow = bm + rowoff + lrow;
            const int brow = bn + rowoff + lrow;
            const unsigned ldsoff = (unsigned)rowoff * 32;  // elements, wave-uniform
            GLOAD16(Ahi_g + (size_t)arow * K + k0 + lk8, &Ah[ldsoff]);
            GLOAD16(Bhi_g + (size_t)brow * K + k0 + lk8, &Bh[ldsoff]);
            if (SPLIT) {
                GLOAD16(Alo_g + (size_t)arow * K + k0 + lk8, &Al[ldsoff]);
                GLOAD16(Blo_g + (size_t)brow * K + k0 + lk8, &Bl[ldsoff]);
            }
        }
        __syncthreads();

        const int fr = lane & 15;
        const int fq = (lane >> 4) * 8;
        short8 ah[4], bh[4], al[4], bl[4];
#pragma unroll
        for (int i = 0; i < 4; ++i) {
            ah[i] = *(const short8*)&Ah[(wm + i * 16 + fr) * 32 + fq];
            if (SPLIT) al[i] = *(const short8*)&Al[(wm + i * 16 + fr) * 32 + fq];
        }
#pragma unroll
        for (int j = 0; j < 4; ++j) {
            bh[j] = *(const short8*)&Bh[(wn + j * 16 + fr) * 32 + fq];
            if (SPLIT) bl[j] = *(const short8*)&Bl[(wn + j * 16 + fr) * 32 + fq];
        }
#pragma unroll
        for (int i = 0; i < 4; ++i)
#pragma unroll
            for (int j = 0; j < 4; ++j) {
                acc[i][j] = __builtin_amdgcn_mfma_f32_16x16x32_bf16(ah[i], bh[j], acc[i][j], 0, 0, 0);
                if (SPLIT) {
                    acc[i][j] = __builtin_amdgcn_mfma_f32_16x16x32_bf16(ah[i], bl[j], acc[i][j], 0, 0, 0);
                    acc[i][j] = __builtin_amdgcn_mfma_f32_16x16x32_bf16(al[i], bh[j], acc[i][j], 0, 0, 0);
                }
            }
        __syncthreads();
    }

    // epilogue: C/D layout col=lane&15, row=(lane>>4)*4+reg
    const int fr = lane & 15;
    const int q4 = (lane >> 4) * 4;
#pragma unroll
    for (int i = 0; i < 4; ++i) {
#pragma unroll
        for (int j = 0; j < 4; ++j) {
            const int col = bn + wn + j * 16 + fr;
            const float bv = bias[col];
#pragma unroll
            for (int r = 0; r < 4; ++r) {
                const int row = bm + wm + i * 16 + q4 + r;
                float v = acc[i][j][r] + bv;
                if (mode == 0) {
                    if (col < 256) out0[(size_t)row * 256 + col] = v;
                    else           out1[(size_t)row * 512 + (col - 256)] = v;
                } else if (mode == 1) {
                    if (col < 256) out0[(size_t)row * 512 + 256 + col] = v;
                    else {
                        v = 0.5f * v * (1.0f + erff(v * 0.70710678118654752f));
                        out1[(size_t)row * 256 + (col - 256)] = v;
                    }
                } else {
                    out0[(size_t)row * 256 + col] = v;
                }
            }
        }
    }
}

// x (fp32) -> hi/lo bf16 pair
__global__ __launch_bounds__(256) void cast_split(
    const float4* __restrict__ x, ushort4* __restrict__ hi,
    ushort4* __restrict__ lo, int n4)
{
    int i = blockIdx.x * 256 + threadIdx.x;
    if (i >= n4) return;
    float4 v = x[i];
    ushort4 h, l;
    h.x = f2bf(v.x); l.x = f2bf(v.x - bf2f(h.x));
    h.y = f2bf(v.y); l.y = f2bf(v.y - bf2f(h.y));
    h.z = f2bf(v.z); l.z = f2bf(v.z - bf2f(h.z));
    h.w = f2bf(v.w); l.w = f2bf(v.w - bf2f(h.w));
    hi[i] = h; lo[i] = l;
}

// fp32 -> bf16
__global__ __launch_bounds__(256) void cast_bf(
    const float4* __restrict__ x, ushort4* __restrict__ o, int n4)
{
    int i = blockIdx.x * 256 + threadIdx.x;
    if (i >= n4) return;
    float4 v = x[i];
    ushort4 h;
    h.x = f2bf(v.x); h.y = f2bf(v.y); h.z = f2bf(v.z); h.w = f2bf(v.w);
    o[i] = h;
}

// Build packed weight/bias buffers.
// Wqk rows: [q_w(256) ; kv_w rows 0..255 (k)] -> hi/lo.  Wvs rows: [kv_w rows 256..511 (v) ; sr_w].
__global__ __launch_bounds__(256) void pack_weights(
    const float* __restrict__ qw, const float* __restrict__ kvw,
    const float* __restrict__ srw, const float* __restrict__ pw,
    const float* __restrict__ qb, const float* __restrict__ kvb,
    const float* __restrict__ srb,
    ushort_t* __restrict__ Wqkh, ushort_t* __restrict__ Wqkl,
    ushort_t* __restrict__ Wvs, ushort_t* __restrict__ Pw,
    float* __restrict__ bqk, float* __restrict__ bvs)
{
    int idx = blockIdx.x * 256 + threadIdx.x;   // grid 512 -> 131072
    if (idx < 131072) {
        int nn = idx >> 8, k = idx & 255;
        float a = (nn < 256) ? qw[nn * 256 + k] : kvw[(nn - 256) * 256 + k];
        unsigned short h = f2bf(a);
        Wqkh[idx] = h;
        Wqkl[idx] = f2bf(a - bf2f(h));
        float b = (nn < 256) ? kvw[(nn + 256) * 256 + k] : srw[(nn - 256) * 256 + k];
        Wvs[idx] = f2bf(b);
    }
    if (idx < 65536) Pw[idx] = f2bf(pw[idx]);
    if (idx < 512) bqk[idx] = (idx < 256) ? qb[idx] : kvb[idx - 256];
    else if (idx < 1024) {
        int r = idx - 512;
        bvs[r] = (r < 256) ? kvb[r + 256] : srb[r - 256];
    }
}

// ------------------------- fp32 tile GEMM (kv_p only) -----------------------
#define BM 64
#define BN 64
#define BKK 16
__global__ __launch_bounds__(256) void gemm_bias_act(
    const float* __restrict__ A, const float* __restrict__ Wt,
    const float* __restrict__ bias, float* __restrict__ Cmat,
    int M, int N, int K, int act)
{
    __shared__ float As[BKK][BM + 4];
    __shared__ float Bs[BKK][BN + 4];
    const int tid = threadIdx.x;
    const int bm = blockIdx.y * BM;
    const int bn = blockIdx.x * BN;
    const int tr = (tid >> 4) << 2;
    const int tc = (tid & 15) << 2;
    const int lr = tid >> 2;
    const int lc = (tid & 3) << 2;
    float acc[4][4] = {{0.f}};

    for (int k0 = 0; k0 < K; k0 += BKK) {
        float4 av = *(const float4*)(A  + (size_t)(bm + lr) * K + k0 + lc);
        float4 wv = *(const float4*)(Wt + (size_t)(bn + lr) * K + k0 + lc);
        As[lc + 0][lr] = av.x; As[lc + 1][lr] = av.y;
        As[lc + 2][lr] = av.z; As[lc + 3][lr] = av.w;
        Bs[lc + 0][lr] = wv.x; Bs[lc + 1][lr] = wv.y;
        Bs[lc + 2][lr] = wv.z; Bs[lc + 3][lr] = wv.w;
        __syncthreads();
#pragma unroll
        for (int kk = 0; kk < BKK; ++kk) {
            float4 a  = *(const float4*)&As[kk][tr];
            float4 bq = *(const float4*)&Bs[kk][tc];
            float av4[4] = {a.x, a.y, a.z, a.w};
            float bv4[4] = {bq.x, bq.y, bq.z, bq.w};
#pragma unroll
            for (int ii = 0; ii < 4; ++ii)
#pragma unroll
                for (int jj = 0; jj < 4; ++jj)
                    acc[ii][jj] = fmaf(av4[ii], bv4[jj], acc[ii][jj]);
        }
        __syncthreads();
    }
#pragma unroll
    for (int ii = 0; ii < 4; ++ii) {
        int m = bm + tr + ii;
#pragma unroll
        for (int jj = 0; jj < 4; ++jj) {
            int nn = bn + tc + jj;
            float v = acc[ii][jj] + bias[nn];
            if (act == 1) v = 0.5f * v * (1.0f + erff(v * 0.70710678118654752f));
            Cmat[(size_t)m * N + nn] = v;
        }
    }
}

// L2-normalize groups of 32 channels within first 256 channels of each row
__global__ __launch_bounds__(256) void headnorm(float* __restrict__ buf, int rowStride)
{
    size_t row = blockIdx.x;
    int tid = threadIdx.x;
    float* p = buf + row * (size_t)rowStride + tid;
    float v = *p;
    float ss = v * v;
#pragma unroll
    for (int off = 16; off; off >>= 1) ss += __shfl_xor(ss, off, 32);
    *p = v / fmaxf(sqrtf(ss), 1e-12f);
}

// 8x8 average pool of x_sr (B,N,C) + LayerNorm -> xpool (B,64,C)
__global__ __launch_bounds__(256) void pool_ln(
    const float* __restrict__ xsr, const float* __restrict__ g,
    const float* __restrict__ be, float* __restrict__ xpool, int Hh, int Ww)
{
    const int C = 256;
    const int Nn = Hh * Ww;
    int b = blockIdx.x >> 6;
    int pidx = blockIdx.x & 63;
    int ph = pidx >> 3, pw = pidx & 7;
    int tid = threadIdx.x;
    float s = 0.f;
    for (int si = 0; si < 8; ++si) {
        int i = ph * 8 + si;
        const float* rowp = xsr + ((size_t)b * Nn + (size_t)i * Ww + pw * 8) * C + tid;
#pragma unroll
        for (int sj = 0; sj < 8; ++sj) s += rowp[(size_t)sj * C];
    }
    s *= (1.f / 64.f);
    __shared__ float red[256];
    red[tid] = s; __syncthreads();
    for (int st = 128; st; st >>= 1) { if (tid < st) red[tid] += red[tid + st]; __syncthreads(); }
    float mean = red[0] * (1.f / 256.f);
    __syncthreads();
    float dv = s - mean;
    red[tid] = dv * dv; __syncthreads();
    for (int st = 128; st; st >>= 1) { if (tid < st) red[tid] += red[tid + st]; __syncthreads(); }
    float var = red[0] * (1.f / 256.f);
    xpool[(size_t)blockIdx.x * C + tid] = dv * rsqrtf(var + 1e-5f) * g[tid] + be[tid];
}

// cpb = relu(table @ fc1^T + b1) @ fc2^T + b2
__global__ __launch_bounds__(256) void cpb_mlp(
    const float* __restrict__ table, const float* __restrict__ w1,
    const float* __restrict__ b1, const float* __restrict__ w2,
    const float* __restrict__ b2, float* __restrict__ outc)
{
    int row = blockIdx.x;
    float t0 = table[(size_t)row * 2], t1 = table[(size_t)row * 2 + 1];
    int tid = threadIdx.x;
    int tid2 = tid + 256;
    float h0 = fmaxf(fmaf(t1, w1[tid * 2 + 1],  fmaf(t0, w1[tid * 2],  b1[tid])),  0.f);
    float h1 = fmaxf(fmaf(t1, w1[tid2 * 2 + 1], fmaf(t0, w1[tid2 * 2], b1[tid2])), 0.f);
    __shared__ float red[256];
    for (int hh = 0; hh < 8; ++hh) {
        red[tid] = h0 * w2[hh * 512 + tid] + h1 * w2[hh * 512 + tid2];
        __syncthreads();
        for (int st = 128; st; st >>= 1) { if (tid < st) red[tid] += red[tid + st]; __syncthreads(); }
        if (tid == 0) outc[(size_t)row * 8 + hh] = red[0] + b2[hh];
        __syncthreads();
    }
}

// ---------------------------------------------------------------------------
// attn_fused_v2 (unchanged from round 2)
// ---------------------------------------------------------------------------
__global__ __launch_bounds__(256) void attn_fused_v2(
    const float* __restrict__ qn, const float* __restrict__ kv,
    const float* __restrict__ kvp, const float* __restrict__ cpbT,
    const int* __restrict__ rpi, const float* __restrict__ sls,
    const float* __restrict__ temp, const float* __restrict__ qe,
    const float* __restrict__ rbl, const float* __restrict__ ltok,
    const float* __restrict__ lbias, float* __restrict__ attno)
{
    const int Hh = 64, Ww = 64, Nn = 4096;
    const int i = blockIdx.x;
    const int h = blockIdx.y;
    const int b = blockIdx.z;
    const int t = threadIdx.x;
    const int w = t >> 6;
    const int lane = t & 63;

    __shared__ float q_s [64][33];
    __shared__ float kp_s[64][36];
    __shared__ float vp_s[64][36];
    __shared__ float oacc[64][33];
    __shared__ float SL [64][10];
    __shared__ float LT [64][10];
    __shared__ float lt_s[288];
    __shared__ float qe_s[32];
    __shared__ float pmax[4][64];
    __shared__ float psum[4][64];

    const float tmp = temp[h];
    const float sp = (tmp > 20.f) ? tmp : log1pf(expf(tmp));

    {
        const int d = t & 31;
        const int jb = t >> 5;
#pragma unroll
        for (int kq = 0; kq < 8; ++kq) {
            const int j = jb + kq * 8;
            const int n = i * 64 + j;
            float qv = qn[((size_t)(b * Nn + n)) * 256 + h * 32 + d];
            q_s[j][d] = (qv + qe[h * 32 + d]) * sp * sls[n];
            const int p = j;
            kp_s[p][d] = kvp[((size_t)(b * 64 + p)) * 512 + h * 32 + d];
            vp_s[p][d] = kvp[((size_t)(b * 64 + p)) * 512 + 256 + h * 32 + d];
        }
        lt_s[t] = ltok[h * 288 + t];
        if (t >= 224 && t < 256) { int u = t - 224 + 256; lt_s[u] = ltok[h * 288 + u]; }
        if (t < 32) qe_s[t] = qe[h * 32 + t];
    }
    __syncthreads();

    {
#pragma unroll
        for (int rep = 0; rep < 3; ++rep) {
            const int task = t + rep * 256;
            if (task < 576) {
                const int j = task / 9, l = task % 9;
                const int ii = i + l / 3 - 1, jj = j + l % 3 - 1;
                const int n = i * 64 + j;
                const float inv_scale = 1.0f / (sp * sls[n]);
                if (ii >= 0 && ii < Hh && jj >= 0 && jj < Ww) {
                    const float* krow = kv + ((size_t)(b * Nn + ii * 64 + jj)) * 512 + h * 32;
                    float dk = 0.f, dl = 0.f;
#pragma unroll
                    for (int dd = 0; dd < 32; dd += 4) {
                        float4 k4 = *(const float4*)(krow + dd);
                        float q0 = q_s[j][dd + 0], q1 = q_s[j][dd + 1];
                        float q2 = q_s[j][dd + 2], q3 = q_s[j][dd + 3];
                        dk += q0 * k4.x + q1 * k4.y + q2 * k4.z + q3 * k4.w;
                        dl += (q0 * inv_scale - qe_s[dd + 0]) * lt_s[(dd + 0) * 9 + l]
                            + (q1 * inv_scale - qe_s[dd + 1]) * lt_s[(dd + 1) * 9 + l]
                            + (q2 * inv_scale - qe_s[dd + 2]) * lt_s[(dd + 2) * 9 + l]
                            + (q3 * inv_scale - qe_s[dd + 3]) * lt_s[(dd + 3) * 9 + l];
                    }
                    SL[j][l] = dk + rbl[h * 9 + l];
                    LT[j][l] = dl + lbias[h * 9 + l];
                } else {
                    SL[j][l] = -INFINITY;
                    LT[j][l] = 0.f;
                }
            }
        }
    }
    __syncthreads();

    const int j = lane;
    const int n64 = (i * 64 + j) * 64;
    float qr[32];
#pragma unroll
    for (int dd = 0; dd < 32; ++dd) qr[dd] = q_s[j][dd];

    float sc[16];
#pragma unroll
    for (int pp = 0; pp < 16; ++pp) {
        const int p = w * 16 + pp;
        const float4* kr = (const float4*)&kp_s[p][0];
        float acc = 0.f;
#pragma unroll
        for (int c = 0; c < 8; ++c) {
            float4 k4 = kr[c];
            acc += qr[4 * c + 0] * k4.x + qr[4 * c + 1] * k4.y
                 + qr[4 * c + 2] * k4.z + qr[4 * c + 3] * k4.w;
        }
        const int idx = rpi[n64 + p];
        sc[pp] = acc + cpbT[(size_t)idx * 8 + h];
    }

    float pm = sc[0];
#pragma unroll
    for (int pp = 1; pp < 16; ++pp) pm = fmaxf(pm, sc[pp]);
    pmax[w][j] = pm;
    __syncthreads();
    float m = fmaxf(fmaxf(pmax[0][j], pmax[1][j]), fmaxf(pmax[2][j], pmax[3][j]));
#pragma unroll
    for (int l = 0; l < 9; ++l) m = fmaxf(m, SL[j][l]);

    float e[16];
    float ps = 0.f;
#pragma unroll
    for (int pp = 0; pp < 16; ++pp) { e[pp] = expf(sc[pp] - m); ps += e[pp]; }
    float el[9];
    if (w == 0) {
#pragma unroll
        for (int l = 0; l < 9; ++l) { el[l] = expf(SL[j][l] - m); ps += el[l]; }
    }
    psum[w][j] = ps;
    __syncthreads();
    const float tot = psum[0][j] + psum[1][j] + psum[2][j] + psum[3][j];
    const float inv = 1.0f / tot;
#pragma unroll
    for (int pp = 0; pp < 16; ++pp) e[pp] *= inv;
    if (w == 0) {
#pragma unroll
        for (int l = 0; l < 9; ++l) SL[j][l] = el[l] * inv + LT[j][l];
    }

    float op[32];
#pragma unroll
    for (int dd = 0; dd < 32; ++dd) op[dd] = 0.f;
#pragma unroll
    for (int pp = 0; pp < 16; ++pp) {
        const int p = w * 16 + pp;
        const float av = e[pp];
        const float4* vr = (const float4*)&vp_s[p][0];
#pragma unroll
        for (int c = 0; c < 8; ++c) {
            float4 v4 = vr[c];
            op[4 * c + 0] += av * v4.x; op[4 * c + 1] += av * v4.y;
            op[4 * c + 2] += av * v4.z; op[4 * c + 3] += av * v4.w;
        }
    }
#pragma unroll
    for (int r = 0; r < 4; ++r) {
        if (w == r) {
            if (r == 0) {
#pragma unroll
                for (int dd = 0; dd < 32; ++dd) oacc[j][dd] = op[dd];
            } else {
#pragma unroll
                for (int dd = 0; dd < 32; ++dd) oacc[j][dd] += op[dd];
            }
        }
        __syncthreads();
    }

    {
        const int d = t & 31;
        const int jb = t >> 5;
#pragma unroll
        for (int kq = 0; kq < 8; ++kq) {
            const int jq = jb + kq * 8;
            float acc = oacc[jq][d];
#pragma unroll
            for (int l = 0; l < 9; ++l) {
                const int ii = i + l / 3 - 1, jj = jq + l % 3 - 1;
                if (ii >= 0 && ii < Hh && jj >= 0 && jj < Ww) {
                    acc += SL[jq][l] *
                        kv[((size_t)(b * Nn + ii * 64 + jj)) * 512 + 256 + h * 32 + d];
                }
            }
            attno[((size_t)(b * Nn + i * 64 + jq)) * 256 + h * 32 + d] = acc;
        }
    }
}

extern "C" void kernel_launch(void* const* d_in, const int* in_sizes, int n_in,
                              void* d_out, int out_size, void* d_ws, size_t ws_size,
                              hipStream_t stream)
{
    const float* x    = (const float*)d_in[0];
    const float* tbl  = (const float*)d_in[1];
    const float* sls  = (const float*)d_in[2];
    const float* q_w  = (const float*)d_in[3];
    const float* q_b  = (const float*)d_in[4];
    const float* kv_w = (const float*)d_in[5];
    const float* kv_b = (const float*)d_in[6];
    const float* temp = (const float*)d_in[7];
    const float* qe   = (const float*)d_in[8];
    const float* sr_w = (const float*)d_in[9];
    const float* sr_b = (const float*)d_in[10];
    const float* ng   = (const float*)d_in[11];
    const float* nb   = (const float*)d_in[12];
    const float* f1w  = (const float*)d_in[13];
    const float* f1b  = (const float*)d_in[14];
    const float* f2w  = (const float*)d_in[15];
    const float* f2b  = (const float*)d_in[16];
    const float* rbl  = (const float*)d_in[17];
    const float* ltok = (const float*)d_in[18];
    const float* lbias= (const float*)d_in[19];
    const float* pw   = (const float*)d_in[20];
    const float* pb   = (const float*)d_in[21];
    const int*   rpi  = (const int*)d_in[22];

    const int C = 256, Hh = 64, Ww = 64, Nn = Hh * Ww;
    const int B = in_sizes[0] / (Nn * C);   // 4
    const int T = in_sizes[1] / 2;
    const int M = B * Nn;                   // 16384

    float* ws = (float*)d_ws;
    size_t o = 0;
    float* qbuf  = ws + o; o += (size_t)M * C;           // 4.19M
    float* kvbuf = ws + o; o += (size_t)M * 2 * C;       // 8.39M
    float* xsr   = ws + o; o += (size_t)M * C;           // 4.19M (later attno)
    float* xpool = ws + o; o += (size_t)B * 64 * C;
    float* kvp   = ws + o; o += (size_t)B * 64 * 2 * C;
    float* cpbB  = ws + o; o += (size_t)T * 8;
    ushort_t* xhi = (ushort_t*)(ws + o); o += (size_t)M * C / 2;   // bf16, reused as attno_bf
    ushort_t* xlo = (ushort_t*)(ws + o); o += (size_t)M * C / 2;
    ushort_t* Wqkh = (ushort_t*)(ws + o); o += 512 * 256 / 2;
    ushort_t* Wqkl = (ushort_t*)(ws + o); o += 512 * 256 / 2;
    ushort_t* Wvs  = (ushort_t*)(ws + o); o += 512 * 256 / 2;
    ushort_t* Pwbf = (ushort_t*)(ws + o); o += 256 * 256 / 2;
    float* bqk = ws + o; o += 512;
    float* bvs = ws + o; o += 512;
    float* attno = xsr;
    ushort_t* attno_bf = xhi;   // xhi dead after the two x-GEMMs

    dim3 blk(256);
    const int n4x = M * C / 4;

    // prepack
    cast_split<<<(n4x + 255) / 256, blk, 0, stream>>>((const float4*)x, (ushort4*)xhi, (ushort4*)xlo, n4x);
    pack_weights<<<512, blk, 0, stream>>>(q_w, kv_w, sr_w, pw, q_b, kv_b, sr_b,
                                          Wqkh, Wqkl, Wvs, Pwbf, bqk, bvs);
    // [q | k] split-precision GEMM; [v | sr] plain GEMM
    mfma_gemm<true ><<<dim3(4, M / 128), blk, 0, stream>>>(xhi, xlo, Wqkh, Wqkl, bqk, qbuf, kvbuf, 0);
    mfma_gemm<false><<<dim3(4, M / 128), blk, 0, stream>>>(xhi, xlo, Wvs,  Wvs,  bvs, kvbuf, xsr, 1);
    // normalize q and k
    headnorm<<<M, blk, 0, stream>>>(qbuf, C);
    headnorm<<<M, blk, 0, stream>>>(kvbuf, 2 * C);
    // pool + LN -> kv_p (fp32 GEMM, tiny) -> normalize k_pool
    pool_ln<<<B * 64, blk, 0, stream>>>(xsr, ng, nb, xpool, Hh, Ww);
    gemm_bias_act<<<dim3(2 * C / BN, (B * 64) / BM), blk, 0, stream>>>(xpool, kv_w, kv_b, kvp, B * 64, 2 * C, C, 0);
    headnorm<<<B * 64, blk, 0, stream>>>(kvp, 2 * C);
    // cpb
    cpb_mlp<<<T, blk, 0, stream>>>(tbl, f1w, f1b, f2w, f2b, cpbB);
    // attention
    attn_fused_v2<<<dim3(Hh, 8, B), blk, 0, stream>>>(
        qbuf, kvbuf, kvp, cpbB, rpi, sls, temp, qe, rbl, ltok, lbias, attno);
    // proj (plain bf16 MFMA)
    cast_bf<<<(n4x + 255) / 256, blk, 0, stream>>>((const float4*)attno, (ushort4*)attno_bf, n4x);
    mfma_gemm<false><<<dim3(2, M / 128), blk, 0, stream>>>(attno_bf, attno_bf, Pwbf, Pwbf, pb, (float*)d_out, (float*)d_out, 2);
}